// Round 11
// baseline (33.712 us; speedup 1.0000x reference)
//
#include <hip/hip_runtime.h>
#include <math.h>

#define BB 4
#define TT 2048
#define DIM 256
#define MROWS (BB*TT)               // 8192
#define MN ((size_t)MROWS*DIM)      // 2097152 elements per tensor
#define SCALE 0.0625f
#define HALF 16

typedef __attribute__((ext_vector_type(8))) short short8;
typedef __attribute__((ext_vector_type(4))) float f32x4;
typedef __attribute__((ext_vector_type(8))) unsigned short ushort8v;

__device__ __forceinline__ ushort f2bf(float f) {
    unsigned u = __builtin_bit_cast(unsigned, f);
    u += 0x7fffu + ((u >> 16) & 1u);
    return (ushort)(u >> 16);
}
__device__ __forceinline__ float bf2f(ushort u) {
    return __builtin_bit_cast(float, (unsigned)u << 16);
}
__device__ __forceinline__ unsigned cvtpk(float lo, float hi) {
    unsigned r;
    asm("v_cvt_pk_bf16_f32 %0, %1, %2" : "=v"(r) : "v"(lo), "v"(hi));
    return r;
}
__device__ __forceinline__ ushort8v pack8(f32x4 lo, f32x4 hi) {
    union { unsigned u[4]; ushort8v v; } r;
    r.u[0] = cvtpk(lo[0], lo[1]);
    r.u[1] = cvtpk(lo[2], lo[3]);
    r.u[2] = cvtpk(hi[0], hi[1]);
    r.u[3] = cvtpk(hi[2], hi[3]);
    return r.v;
}

#define GLOAD16(g, l) __builtin_amdgcn_global_load_lds( \
    (const __attribute__((address_space(1))) void*)(g), \
    (__attribute__((address_space(3))) void*)(l), 16, 0, 0)

// part layout: idx = (((which*4+b)*2+sum)*256 + col)*16 + mb_local. Overwrite-only.

// ---------------- MFMA GEMM (r9 structure, verbatim) ----------------
#define A_TILE (128*64)
#define B_TILE (256*64)
__global__ __launch_bounds__(512) void gemm_kernel(
    const float* __restrict__ x,
    const float* __restrict__ Wq, const float* __restrict__ Wk, const float* __restrict__ Wv,
    const float* __restrict__ bq, const float* __restrict__ bk, const float* __restrict__ bv,
    ushort* __restrict__ qkv, float* __restrict__ part, float* __restrict__ out)
{
    __shared__ ushort As[2 * A_TILE];   // 32 KB
    __shared__ ushort Bs[2 * B_TILE];   // 64 KB
    __shared__ float sred[2][2][256];   // 8 KB

    int tid = threadIdx.x;
    int lane = tid & 63, w = tid >> 6;      // 8 waves
    int wr = w >> 2, wc = w & 3;            // 2 x 4

    int orig = blockIdx.x + blockIdx.y * 64;
    if (orig == 0) {
        out[tid] = 0.f; out[512 + tid] = 0.f;   // attn is a later dispatch: race-free
    }

    int wg = (orig & 7) * 24 + (orig >> 3);
    int mb = wg / 3, nb = wg % 3;
    int m0 = mb * 128;
    int which = nb;

    const float* Wm   = which == 0 ? Wq : (which == 1 ? Wk : Wv);
    const float* bias = which == 0 ? bq : (which == 1 ? bk : bv);

    int srow = lane >> 3;
    int sc   = lane & 7;
    int kof  = (sc ^ srow) << 3;
    const float* aRow = x  + (size_t)(m0 + w * 16 + srow) * DIM + kof;
    const float* bRow = Wm + (size_t)(w * 32 + srow) * DIM + kof;
    int aBase = (w * 16 + srow) * 64 + sc * 8;
    int bBase = (w * 32 + srow) * 64 + sc * 8;

    f32x4 acc[4][4] = {};
    f32x4 ra[2][2], rb[4][2];

    auto loadT = [&](int kt) {
        int ko = kt * 64;
        #pragma unroll
        for (int g = 0; g < 2; g++) {
            ra[g][0] = *(const f32x4*)(aRow + (size_t)g * 8 * DIM + ko);
            ra[g][1] = *(const f32x4*)(aRow + (size_t)g * 8 * DIM + ko + 4);
        }
        #pragma unroll
        for (int g = 0; g < 4; g++) {
            rb[g][0] = *(const f32x4*)(bRow + (size_t)g * 8 * DIM + ko);
            rb[g][1] = *(const f32x4*)(bRow + (size_t)g * 8 * DIM + ko + 4);
        }
    };
    auto commitT = [&](int buf) {
        ushort* Ab = &As[buf * A_TILE];
        ushort* Bb = &Bs[buf * B_TILE];
        #pragma unroll
        for (int g = 0; g < 2; g++)
            *(ushort8v*)(&Ab[aBase + g * 8 * 64]) = pack8(ra[g][0], ra[g][1]);
        #pragma unroll
        for (int g = 0; g < 4; g++)
            *(ushort8v*)(&Bb[bBase + g * 8 * 64]) = pack8(rb[g][0], rb[g][1]);
    };

    int fr = lane & 15, fp = lane >> 4, swz = lane & 7;

    loadT(0);
    commitT(0);
    __syncthreads();
    int cur = 0;
    #pragma unroll
    for (int kt = 0; kt < 4; kt++) {
        if (kt < 3) loadT(kt + 1);
        const ushort* a_lds = &As[cur * A_TILE];
        const ushort* b_lds = &Bs[cur * B_TILE];
        #pragma unroll
        for (int ks = 0; ks < 2; ks++) {
            short8 af[4], bf[4];
            #pragma unroll
            for (int i = 0; i < 4; i++) {
                int row = wr * 64 + i * 16 + fr;
                int slot = ks * 4 + fp;
                af[i] = *(const short8*)(&a_lds[row * 64 + ((slot ^ swz) << 3)]);
            }
            #pragma unroll
            for (int j = 0; j < 4; j++) {
                int row = wc * 64 + j * 16 + fr;
                int slot = ks * 4 + fp;
                bf[j] = *(const short8*)(&b_lds[row * 64 + ((slot ^ swz) << 3)]);
            }
            #pragma unroll
            for (int i = 0; i < 4; i++)
                #pragma unroll
                for (int j = 0; j < 4; j++)
                    acc[i][j] = __builtin_amdgcn_mfma_f32_16x16x32_bf16(
                        af[i], bf[j], acc[i][j], 0, 0, 0);
        }
        if (kt < 3) commitT(cur ^ 1);
        __syncthreads();
        cur ^= 1;
    }

    int b_idx = mb >> 4;
    int mb_local = mb & 15;
    #pragma unroll
    for (int j = 0; j < 4; j++) {
        int col = wc * 64 + j * 16 + fr;
        float bb = bias[col];
        float s1 = 0.f, s2 = 0.f;
        ushort* outbase = qkv + (size_t)which * MN + col;
        #pragma unroll
        for (int i = 0; i < 4; i++) {
            #pragma unroll
            for (int rr = 0; rr < 4; rr++) {
                int row = m0 + wr * 64 + i * 16 + fp * 4 + rr;
                float y = acc[i][j][rr] + bb;
                ushort ub = f2bf(y);
                outbase[(size_t)row * DIM] = ub;
                float yr = bf2f(ub);
                s1 += yr; s2 += yr * yr;
            }
        }
        s1 += __shfl_xor(s1, 16, 64); s1 += __shfl_xor(s1, 32, 64);
        s2 += __shfl_xor(s2, 16, 64); s2 += __shfl_xor(s2, 32, 64);
        if (fp == 0) { sred[0][wr][col] = s1; sred[1][wr][col] = s2; }
    }
    __syncthreads();
    if (tid < 256) {
        float p1 = sred[0][0][tid] + sred[0][1][tid];
        float p2 = sred[1][0][tid] + sred[1][1][tid];
        int wb = which * 4 + b_idx;
        part[((size_t)(wb * 2 + 0) * 256 + tid) * 16 + mb_local] = p1;
        part[((size_t)(wb * 2 + 1) * 256 + tid) * 16 + mb_local] = p2;
    }
}

// ---------------- banded attention (r9 structure, verbatim) ----------------
__global__ __launch_bounds__(256) void attn_kernel(const ushort* __restrict__ qkv,
                                                   const float* __restrict__ part,
                                                   float* __restrict__ out)
{
    int orig = blockIdx.x + blockIdx.y * 64;
    int wg = (orig & 7) * 32 + (orig >> 3);
    int tile = wg & 63, b = wg >> 6;
    int t0 = tile * 32;

    const ushort* qg = qkv;
    const ushort* kg = qkv + MN;
    const ushort* vg = qkv + 2 * MN;

    __shared__ ushort Qs[32 * 256];
    __shared__ ushort Ks[64 * 256];
    __shared__ float Ps[32][65];
    __shared__ float csp[4][64];
    __shared__ float qsc[256], qsh[256];

    int tid = threadIdx.x;
    int lane = tid & 63, w = tid >> 6;

    {
        int r0 = lane >> 5;
        int sp = lane & 31;
        #pragma unroll
        for (int i = 0; i < 8; i++) {
            int rowbase = (w * 8 + i) * 2;
            int r = rowbase + r0;
            int gt = t0 - HALF + r;
            int gtc = gt < 0 ? 0 : (gt > TT - 1 ? TT - 1 : gt);
            int s = sp ^ (r & 7);
            GLOAD16(kg + (size_t)(b * TT + gtc) * DIM + s * 8, &Ks[rowbase * 256]);
        }
    }

    float sums[3][2];
    #pragma unroll
    for (int wq = 0; wq < 3; wq++) {
        #pragma unroll
        for (int sm = 0; sm < 2; sm++) {
            const float* p = part + ((size_t)((wq * 4 + b) * 2 + sm) * 256 + tid) * 16;
            float a = 0.f;
            #pragma unroll
            for (int m4 = 0; m4 < 4; m4++) {
                f32x4 v = *(const f32x4*)(p + m4 * 4);
                a += (v[0] + v[1]) + (v[2] + v[3]);
            }
            sums[wq][sm] = a;
        }
    }
    float mq = sums[0][0] * (1.f / 2048.f);
    float rq = 1.f / sqrtf(sums[0][1] * (1.f / 2048.f) - mq * mq + 1e-5f);
    float mk = sums[1][0] * (1.f / 2048.f);
    float rk = 1.f / sqrtf(sums[1][1] * (1.f / 2048.f) - mk * mk + 1e-5f);
    float mv = sums[2][0] * (1.f / 2048.f);
    float rv = 1.f / sqrtf(sums[2][1] * (1.f / 2048.f) - mv * mv + 1e-5f);
    float qs = rq * rk;
    qsc[tid] = qs;  qsh[tid] = -mq * qs;
    float vscr = rv, vshr = -mv * rv;
    __syncthreads();

    #pragma unroll
    for (int i = 0; i < 4; i++) {
        int idx = tid + i * 256;
        int qr = idx >> 5, sp = idx & 31;
        int h0 = sp * 8;
        ushort8v raw = *(const ushort8v*)(qg + ((size_t)(b * TT + t0 + qr)) * DIM + h0);
        ushort8v o;
        #pragma unroll
        for (int e = 0; e < 8; e++)
            o[e] = f2bf(bf2f(raw[e]) * qsc[h0 + e] + qsh[h0 + e]);
        *(ushort8v*)(&Qs[qr * 256 + ((sp ^ (qr & 7)) << 3)]) = o;
    }
    __syncthreads();

    f32x4 sacc[2] = {};
    int fr = lane & 15, fp = lane >> 4, swz = lane & 7;
    int brow = w * 16 + fr;
    #pragma unroll
    for (int ks = 0; ks < 8; ks++) {
        int slot = ks * 4 + fp;
        short8 bfr = *(const short8*)(&Ks[brow * 256 + ((slot ^ swz) << 3)]);
        #pragma unroll
        for (int rf = 0; rf < 2; rf++) {
            int arow = rf * 16 + fr;
            short8 af = *(const short8*)(&Qs[arow * 256 + ((slot ^ swz) << 3)]);
            sacc[rf] = __builtin_amdgcn_mfma_f32_16x16x32_bf16(af, bfr, sacc[rf], 0, 0, 0);
        }
    }
    #pragma unroll
    for (int rf = 0; rf < 2; rf++)
        #pragma unroll
        for (int rr = 0; rr < 4; rr++)
            Ps[rf * 16 + fp * 4 + rr][w * 16 + fr] = sacc[rf][rr];
    __syncthreads();

    int r = tid >> 3, c0 = (tid & 7) * 8;
    float sv[8];
    float mx = -1e30f;
    #pragma unroll
    for (int j = 0; j < 8; j++) {
        int c = c0 + j;
        int gt = t0 - HALF + c;
        bool valid = (c >= r) && (c <= r + 32) && (gt >= 0) && (gt < TT);
        sv[j] = valid ? Ps[r][c] * SCALE : -1e30f;
        mx = fmaxf(mx, sv[j]);
    }
    #pragma unroll
    for (int d = 1; d < 8; d <<= 1) mx = fmaxf(mx, __shfl_xor(mx, d, 64));
    float sum = 0.f;
    #pragma unroll
    for (int j = 0; j < 8; j++) { sv[j] = __expf(sv[j] - mx); sum += sv[j]; }
    #pragma unroll
    for (int d = 1; d < 8; d <<= 1) sum += __shfl_xor(sum, d, 64);
    float inv = 1.0f / sum;
    #pragma unroll
    for (int j = 0; j < 8; j++) Ps[r][c0 + j] = sv[j] * inv;
    __syncthreads();

    {
        int c = tid & 63, rq4 = tid >> 6;
        float s = 0.f;
        #pragma unroll
        for (int j = 0; j < 8; j++) s += Ps[rq4 * 8 + j][c];
        csp[rq4][c] = s;
    }
    __syncthreads();

    int h = tid;
    const ushort* vrow = vg + (size_t)b * TT * DIM + h;
    float o = 0.f;
    #pragma unroll 8
    for (int c = 0; c < 64; c++) {
        float cs = csp[0][c] + csp[1][c] + csp[2][c] + csp[3][c];
        int gt = t0 - HALF + c;
        int gtc = gt < 0 ? 0 : (gt > TT - 1 ? TT - 1 : gt);
        o += cs * bf2f(vrow[(size_t)gtc * DIM]);
    }
    o = vscr * o + 32.f * vshr;
    atomicAdd(&out[(size_t)b * DIM + h], o * (1.0f / TT));
}

extern "C" void kernel_launch(void* const* d_in, const int* in_sizes, int n_in,
                              void* d_out, int out_size, void* d_ws, size_t ws_size,
                              hipStream_t stream) {
    const float* x  = (const float*)d_in[0];
    const float* Wq = (const float*)d_in[1];
    const float* bq = (const float*)d_in[2];
    const float* Wk = (const float*)d_in[3];
    const float* bk = (const float*)d_in[4];
    const float* Wv = (const float*)d_in[5];
    const float* bv = (const float*)d_in[6];
    float* out = (float*)d_out;

    ushort* qkv   = (ushort*)d_ws;                 // 3*MN ushorts (12.6 MB)
    float* part   = (float*)(qkv + 3 * MN);        // 98304 floats, overwrite-only
    float* probeo = part + 98304;                  // 1024 floats scratch (probe output)

    gemm_kernel<<<dim3(64, 3), 512, 0, stream>>>(x, Wq, Wk, Wv, bq, bk, bv, qkv, part, out);
    attn_kernel<<<dim3(64, 4), 256, 0, stream>>>(qkv, part, out);
    // TIMING PROBE: identical attn dispatch to scratch output -> dur delta == T_attn.
    attn_kernel<<<dim3(64, 4), 256, 0, stream>>>(qkv, part, probeo);
}

// Round 12
// 23.754 us; speedup vs baseline: 1.4192x; 1.4192x over previous
//
#include <hip/hip_runtime.h>
#include <math.h>

#define BB 4
#define TT 2048
#define DIM 256
#define MROWS (BB*TT)               // 8192
#define MN ((size_t)MROWS*DIM)      // 2097152 elements per tensor
#define SCALE 0.0625f
#define HALF 16

typedef __attribute__((ext_vector_type(8))) short short8;
typedef __attribute__((ext_vector_type(4))) float f32x4;
typedef __attribute__((ext_vector_type(8))) unsigned short ushort8v;

__device__ __forceinline__ ushort f2bf(float f) {
    unsigned u = __builtin_bit_cast(unsigned, f);
    u += 0x7fffu + ((u >> 16) & 1u);
    return (ushort)(u >> 16);
}
__device__ __forceinline__ float bf2f(ushort u) {
    return __builtin_bit_cast(float, (unsigned)u << 16);
}
__device__ __forceinline__ unsigned cvtpk(float lo, float hi) {
    unsigned r;
    asm("v_cvt_pk_bf16_f32 %0, %1, %2" : "=v"(r) : "v"(lo), "v"(hi));
    return r;
}
__device__ __forceinline__ ushort8v pack8(f32x4 lo, f32x4 hi) {
    union { unsigned u[4]; ushort8v v; } r;
    r.u[0] = cvtpk(lo[0], lo[1]);
    r.u[1] = cvtpk(lo[2], lo[3]);
    r.u[2] = cvtpk(hi[0], hi[1]);
    r.u[3] = cvtpk(hi[2], hi[3]);
    return r.v;
}

#define GLOAD16(g, l) __builtin_amdgcn_global_load_lds( \
    (const __attribute__((address_space(1))) void*)(g), \
    (__attribute__((address_space(3))) void*)(l), 16, 0, 0)

// part layout: idx = (((which*4+b)*2+sum)*256 + col)*16 + mb_local. Overwrite-only.

// ---------------- MFMA GEMM ----------------
// BM=128, BN=192, BK=64; grid 64m x 4n = 256 blocks = exactly 1/CU.
// 512 threads = 8 waves (2m x 4n), wave tile 64x48 (acc[4][3]).
// 16-col fragments / 8-row staging groups never straddle the 256-col tensor
// boundary (both aligned to 16/8), so tensor selection is fragment-uniform.
#define A_TILE (128*64)
#define B_TILE (192*64)
__global__ __launch_bounds__(512) void gemm_kernel(
    const float* __restrict__ x,
    const float* __restrict__ Wq, const float* __restrict__ Wk, const float* __restrict__ Wv,
    const float* __restrict__ bq, const float* __restrict__ bk, const float* __restrict__ bv,
    ushort* __restrict__ qkv, float* __restrict__ part, float* __restrict__ out)
{
    __shared__ ushort As[2 * A_TILE];   // 32 KB
    __shared__ ushort Bs[2 * B_TILE];   // 48 KB
    __shared__ float sred[2][2][192];   // 3 KB

    int tid = threadIdx.x;
    int lane = tid & 63, w = tid >> 6;      // 8 waves
    int wr = w >> 2, wc = w & 3;            // 2 x 4

    int orig = blockIdx.x;
    if (orig == 0) {
        out[tid] = 0.f; out[512 + tid] = 0.f;   // attn is a later dispatch: race-free
    }

    // XCD-aware remap: 256 blocks, 8 XCDs, 32/XCD (8 contiguous m-panels + all W).
    int wg = (orig & 7) * 32 + (orig >> 3);
    int mb = wg >> 2, nt = wg & 3;
    int m0 = mb * 128, n0 = nt * 192;

    int srow = lane >> 3;                 // 0..7 == row&7
    int sc   = lane & 7;                  // linear 16B slot
    int kof  = (sc ^ srow) << 3;          // swizzled source k-offset
    const float* aRow = x + (size_t)(m0 + w * 16 + srow) * DIM + kof;
    // B rows: wave w covers global cols [n0+w*24, +24) in 3 groups of 8
    const float* bRowP[3];
    #pragma unroll
    for (int g = 0; g < 3; g++) {
        int grow = n0 + w * 24 + g * 8 + srow;
        int whr = grow >> 8;
        const float* Wr = whr == 0 ? Wq : (whr == 1 ? Wk : Wv);
        bRowP[g] = Wr + (size_t)(grow & 255) * DIM + kof;
    }
    int aBase = (w * 16 + srow) * 64 + sc * 8;
    int bBase = (w * 24 + srow) * 64 + sc * 8;

    f32x4 acc[4][3] = {};
    f32x4 ra[2][2], rb[3][2];

    auto loadT = [&](int kt) {
        int ko = kt * 64;
        #pragma unroll
        for (int g = 0; g < 2; g++) {
            ra[g][0] = *(const f32x4*)(aRow + (size_t)g * 8 * DIM + ko);
            ra[g][1] = *(const f32x4*)(aRow + (size_t)g * 8 * DIM + ko + 4);
        }
        #pragma unroll
        for (int g = 0; g < 3; g++) {
            rb[g][0] = *(const f32x4*)(bRowP[g] + ko);
            rb[g][1] = *(const f32x4*)(bRowP[g] + ko + 4);
        }
    };
    auto commitT = [&](int buf) {
        ushort* Ab = &As[buf * A_TILE];
        ushort* Bb = &Bs[buf * B_TILE];
        #pragma unroll
        for (int g = 0; g < 2; g++)
            *(ushort8v*)(&Ab[aBase + g * 8 * 64]) = pack8(ra[g][0], ra[g][1]);
        #pragma unroll
        for (int g = 0; g < 3; g++)
            *(ushort8v*)(&Bb[bBase + g * 8 * 64]) = pack8(rb[g][0], rb[g][1]);
    };

    int fr = lane & 15, fp = lane >> 4, swz = lane & 7;

    loadT(0);
    commitT(0);
    __syncthreads();
    int cur = 0;
    #pragma unroll
    for (int kt = 0; kt < 4; kt++) {
        if (kt < 3) loadT(kt + 1);         // global loads in flight during MFMA
        const ushort* a_lds = &As[cur * A_TILE];
        const ushort* b_lds = &Bs[cur * B_TILE];
        #pragma unroll
        for (int ks = 0; ks < 2; ks++) {
            short8 af[4], bf[3];
            #pragma unroll
            for (int i = 0; i < 4; i++) {
                int row = wr * 64 + i * 16 + fr;
                int slot = ks * 4 + fp;
                af[i] = *(const short8*)(&a_lds[row * 64 + ((slot ^ swz) << 3)]);
            }
            #pragma unroll
            for (int j = 0; j < 3; j++) {
                int row = wc * 48 + j * 16 + fr;
                int slot = ks * 4 + fp;
                bf[j] = *(const short8*)(&b_lds[row * 64 + ((slot ^ swz) << 3)]);
            }
            #pragma unroll
            for (int i = 0; i < 4; i++)
                #pragma unroll
                for (int j = 0; j < 3; j++)
                    acc[i][j] = __builtin_amdgcn_mfma_f32_16x16x32_bf16(
                        af[i], bf[j], acc[i][j], 0, 0, 0);
        }
        if (kt < 3) commitT(cur ^ 1);      // packed convert + ds_write next buffer
        __syncthreads();
        cur ^= 1;
    }

    // epilogue: bias, round, store qkv; column sums -> sred -> non-overlapping partials
    int b_idx = mb >> 4;                   // 16 m-blocks per batch
    int mb_local = mb & 15;
    #pragma unroll
    for (int j = 0; j < 3; j++) {
        int lstart = wc * 48 + j * 16;     // local frag start (never straddles 256)
        int gstart = n0 + lstart;
        int whf = gstart >> 8;             // fragment-uniform tensor id
        int hbase = gstart & 255;
        const float* bias = whf == 0 ? bq : (whf == 1 ? bk : bv);
        int h = hbase + fr;
        float bb = bias[h];
        float s1 = 0.f, s2 = 0.f;
        ushort* outbase = qkv + (size_t)whf * MN + h;
        #pragma unroll
        for (int i = 0; i < 4; i++) {
            #pragma unroll
            for (int rr = 0; rr < 4; rr++) {
                int row = m0 + wr * 64 + i * 16 + fp * 4 + rr;
                float y = acc[i][j][rr] + bb;
                ushort ub = f2bf(y);
                outbase[(size_t)row * DIM] = ub;
                float yr = bf2f(ub);
                s1 += yr; s2 += yr * yr;
            }
        }
        s1 += __shfl_xor(s1, 16, 64); s1 += __shfl_xor(s1, 32, 64);
        s2 += __shfl_xor(s2, 16, 64); s2 += __shfl_xor(s2, 32, 64);
        if (fp == 0) { sred[0][wr][lstart + fr] = s1; sred[1][wr][lstart + fr] = s2; }
    }
    __syncthreads();
    if (tid < 192) {
        float p1 = sred[0][0][tid] + sred[0][1][tid];
        float p2 = sred[1][0][tid] + sred[1][1][tid];
        int gcol = n0 + tid;
        int whc = gcol >> 8, h = gcol & 255;
        int wb = whc * 4 + b_idx;
        part[((size_t)(wb * 2 + 0) * 256 + h) * 16 + mb_local] = p1;
        part[((size_t)(wb * 2 + 1) * 256 + h) * 16 + mb_local] = p2;
    }
}

// ---------------- banded attention: early K+V gload_lds, csum fold ----------------
__global__ __launch_bounds__(256) void attn_kernel(const ushort* __restrict__ qkv,
                                                   const float* __restrict__ part,
                                                   float* __restrict__ out)
{
    int orig = blockIdx.x + blockIdx.y * 64;
    int wg = (orig & 7) * 32 + (orig >> 3);
    int tile = wg & 63, b = wg >> 6;
    int t0 = tile * 32;

    const ushort* qg = qkv;
    const ushort* kg = qkv + MN;
    const ushort* vg = qkv + 2 * MN;

    __shared__ ushort Qs[32 * 256];   // q*(rq*rk), bf16, swizzled slots
    __shared__ ushort Ks[64 * 256];   // RAW k, swizzled via pre-swizzled global src
    __shared__ ushort Vs[64 * 256];   // RAW v, linear
    __shared__ float Ps[32][65];
    __shared__ float csp[4][64];
    __shared__ float csum[64];
    __shared__ float qsc[256], qsh[256];

    int tid = threadIdx.x;
    int lane = tid & 63, w = tid >> 6;

    // (1) issue RAW K (pre-swizzled src) + RAW V (linear) direct-to-LDS at start
    {
        int r0 = lane >> 5;
        int sp = lane & 31;
        #pragma unroll
        for (int i = 0; i < 8; i++) {
            int rowbase = (w * 8 + i) * 2;
            int r = rowbase + r0;
            int gt = t0 - HALF + r;
            int gtc = gt < 0 ? 0 : (gt > TT - 1 ? TT - 1 : gt);   // clamped rows get csum==0
            int s = sp ^ (r & 7);
            GLOAD16(kg + (size_t)(b * TT + gtc) * DIM + s * 8, &Ks[rowbase * 256]);
            GLOAD16(vg + (size_t)(b * TT + gtc) * DIM + sp * 8, &Vs[rowbase * 256]);
        }
    }

    // (2) reduce stat partials (fixed order -> deterministic), h = tid
    float sums[3][2];
    #pragma unroll
    for (int wq = 0; wq < 3; wq++) {
        #pragma unroll
        for (int sm = 0; sm < 2; sm++) {
            const float* p = part + ((size_t)((wq * 4 + b) * 2 + sm) * 256 + tid) * 16;
            float a = 0.f;
            #pragma unroll
            for (int m4 = 0; m4 < 4; m4++) {
                f32x4 v = *(const f32x4*)(p + m4 * 4);
                a += (v[0] + v[1]) + (v[2] + v[3]);
            }
            sums[wq][sm] = a;
        }
    }
    float mq = sums[0][0] * (1.f / 2048.f);
    float rq = 1.f / sqrtf(sums[0][1] * (1.f / 2048.f) - mq * mq + 1e-5f);
    float mk = sums[1][0] * (1.f / 2048.f);
    float rk = 1.f / sqrtf(sums[1][1] * (1.f / 2048.f) - mk * mk + 1e-5f);
    float mv = sums[2][0] * (1.f / 2048.f);
    float rv = 1.f / sqrtf(sums[2][1] * (1.f / 2048.f) - mv * mv + 1e-5f);
    float qs = rq * rk;
    qsc[tid] = qs;  qsh[tid] = -mq * qs;
    float vscr = rv, vshr = -mv * rv;
    __syncthreads();

    // (3) stage Q (32x256) scaled; K/V gloads still in flight
    #pragma unroll
    for (int i = 0; i < 4; i++) {
        int idx = tid + i * 256;
        int qr = idx >> 5, sp = idx & 31;
        int h0 = sp * 8;
        ushort8v raw = *(const ushort8v*)(qg + ((size_t)(b * TT + t0 + qr)) * DIM + h0);
        ushort8v o;
        #pragma unroll
        for (int e = 0; e < 8; e++)
            o[e] = f2bf(bf2f(raw[e]) * qsc[h0 + e] + qsh[h0 + e]);
        *(ushort8v*)(&Qs[qr * 256 + ((sp ^ (qr & 7)) << 3)]) = o;
    }
    __syncthreads();   // drains Q ds_writes + K/V gload_lds

    // (4) MFMA scores 32x64
    f32x4 sacc[2] = {};
    int fr = lane & 15, fp = lane >> 4, swz = lane & 7;
    int brow = w * 16 + fr;
    #pragma unroll
    for (int ks = 0; ks < 8; ks++) {
        int slot = ks * 4 + fp;
        short8 bfr = *(const short8*)(&Ks[brow * 256 + ((slot ^ swz) << 3)]);
        #pragma unroll
        for (int rf = 0; rf < 2; rf++) {
            int arow = rf * 16 + fr;
            short8 af = *(const short8*)(&Qs[arow * 256 + ((slot ^ swz) << 3)]);
            sacc[rf] = __builtin_amdgcn_mfma_f32_16x16x32_bf16(af, bfr, sacc[rf], 0, 0, 0);
        }
    }
    #pragma unroll
    for (int rf = 0; rf < 2; rf++)
        #pragma unroll
        for (int rr = 0; rr < 4; rr++)
            Ps[rf * 16 + fp * 4 + rr][w * 16 + fr] = sacc[rf][rr];
    __syncthreads();

    // (5) softmax: thread (r = tid>>3) owns cols c0..c0+7
    int r = tid >> 3, c0 = (tid & 7) * 8;
    float sv[8];
    float mx = -1e30f;
    #pragma unroll
    for (int j = 0; j < 8; j++) {
        int c = c0 + j;
        int gt = t0 - HALF + c;
        bool valid = (c >= r) && (c <= r + 32) && (gt >= 0) && (gt < TT);
        sv[j] = valid ? Ps[r][c] * SCALE : -1e30f;
        mx = fmaxf(mx, sv[j]);
    }
    #pragma unroll
    for (int d = 1; d < 8; d <<= 1) mx = fmaxf(mx, __shfl_xor(mx, d, 64));
    float sum = 0.f;
    #pragma unroll
    for (int j = 0; j < 8; j++) { sv[j] = __expf(sv[j] - mx); sum += sv[j]; }
    #pragma unroll
    for (int d = 1; d < 8; d <<= 1) sum += __shfl_xor(sum, d, 64);
    float inv = 1.0f / sum;
    #pragma unroll
    for (int j = 0; j < 8; j++) Ps[r][c0 + j] = sv[j] * inv;
    __syncthreads();

    // (6) partial column sums of P, then fold to csum
    {
        int c = tid & 63, rq4 = tid >> 6;
        float s = 0.f;
        #pragma unroll
        for (int j = 0; j < 8; j++) s += Ps[rq4 * 8 + j][c];
        csp[rq4][c] = s;
    }
    __syncthreads();
    if (tid < 64) csum[tid] = csp[0][tid] + csp[1][tid] + csp[2][tid] + csp[3][tid];
    __syncthreads();

    // (7) PV from LDS V (latency was hidden under phases 2-5)
    int h = tid;
    float o = 0.f;
    #pragma unroll 8
    for (int c = 0; c < 64; c++)
        o += csum[c] * bf2f(Vs[c * 256 + h]);
    o = vscr * o + 32.f * vshr;
    atomicAdd(&out[(size_t)b * DIM + h], o * (1.0f / TT));
}

extern "C" void kernel_launch(void* const* d_in, const int* in_sizes, int n_in,
                              void* d_out, int out_size, void* d_ws, size_t ws_size,
                              hipStream_t stream) {
    const float* x  = (const float*)d_in[0];
    const float* Wq = (const float*)d_in[1];
    const float* bq = (const float*)d_in[2];
    const float* Wk = (const float*)d_in[3];
    const float* bk = (const float*)d_in[4];
    const float* Wv = (const float*)d_in[5];
    const float* bv = (const float*)d_in[6];
    float* out = (float*)d_out;

    ushort* qkv  = (ushort*)d_ws;                 // 3*MN ushorts (12.6 MB)
    float* part  = (float*)(qkv + 3 * MN);        // 98304 floats, overwrite-only

    gemm_kernel<<<dim3(256), 512, 0, stream>>>(x, Wq, Wk, Wv, bq, bk, bv, qkv, part, out);
    attn_kernel<<<dim3(64, 4), 256, 0, stream>>>(qkv, part, out);
}